// Round 17
// baseline (155.663 us; speedup 1.0000x reference)
//
#include <hip/hip_runtime.h>

#define HBITS 19u
#define HSIZE (1u << HBITS)
#define HMASK (HSIZE - 1u)
#define MAXD  27                  // geometric max neighbors (26) + slack
#define EMPTY64 0xFFFFFFFFFFFFFFFFull

constexpr int CD = 41, CH = 1024, CW = 1024;

// ---------------- setup: clear hash table + deg; 16 extra blocks: T = W0c@W1c ------

__global__ __launch_bounds__(256) void setup(unsigned long long* __restrict__ tab,
                                             int* __restrict__ deg, int n,
                                             const float* __restrict__ Ws,
                                             float* __restrict__ T,
                                             int nfill) {
    if ((int)blockIdx.x >= nfill) {
        // parallel weight product, mm64-style: 1 elem/thread, dual chains
        int e = ((int)blockIdx.x - nfill) * 256 + threadIdx.x;   // 0..4095
        int r = e >> 6, c = e & 63;
        const float* W0 = Ws + (0 * 27 + 13) * 4096;
        const float* W1 = Ws + (1 * 27 + 13) * 4096;
        float s0 = 0.f, s1 = 0.f;
#pragma unroll
        for (int k = 0; k < 64; k += 2) {
            s0 = fmaf(W0[r * 64 + k],     W1[k * 64 + c],       s0);
            s1 = fmaf(W0[r * 64 + k + 1], W1[(k + 1) * 64 + c], s1);
        }
        T[e] = s0 + s1;
        return;
    }
    unsigned i = blockIdx.x * 256u + threadIdx.x;
    if (i < HSIZE) tab[i] = EMPTY64;
    if (i < (unsigned)n) deg[i] = 0;
}

// ---------------- hash insert; 16 extra blocks: P = T@W2c ----------------

__global__ __launch_bounds__(256) void hash_insert(const int* __restrict__ coors, int n,
                                                   unsigned long long* __restrict__ tab,
                                                   const float* __restrict__ T,
                                                   const float* __restrict__ Ws,
                                                   float* __restrict__ P,
                                                   int nins) {
    if ((int)blockIdx.x >= nins) {
        int e = ((int)blockIdx.x - nins) * 256 + threadIdx.x;    // 0..4095
        int r = e >> 6, c = e & 63;
        const float* W2 = Ws + (2 * 27 + 13) * 4096;
        float s0 = 0.f, s1 = 0.f;
#pragma unroll
        for (int k = 0; k < 64; k += 2) {
            s0 = fmaf(T[r * 64 + k],     W2[k * 64 + c],       s0);
            s1 = fmaf(T[r * 64 + k + 1], W2[(k + 1) * 64 + c], s1);
        }
        P[e] = s0 + s1;
        return;
    }
    int i = blockIdx.x * 256 + threadIdx.x;
    if (i >= n) return;
    int b = coors[4 * i], z = coors[4 * i + 1], y = coors[4 * i + 2], x = coors[4 * i + 3];
    unsigned lin = (((unsigned)b * CD + (unsigned)z) * CH + (unsigned)y) * CW + (unsigned)x;
    unsigned h = (lin * 2654435761u) >> (32u - HBITS);
    unsigned long long rec = ((unsigned long long)(unsigned)i << 32) | (unsigned long long)lin;
    while (true) {
        unsigned long long prev = atomicCAS(&tab[h], EMPTY64, rec);
        if (prev == EMPTY64) break;
        h = (h + 1u) & HMASK;
    }
}

// ---------------- adjacency build: one thread per point, 13 ILP-batched probes -----
// Fully-unrolled k loop -> 13 independent first-probe loads in flight (batched by
// the compiler); ~80% of taps resolve on probe 0 at load factor 0.23; rare
// collisions fall into the scalar probe loop. Semantics identical to hash_lookup.
// Scattered atomics only (R8-verified).

__global__ __launch_bounds__(256) void build_adj(const int* __restrict__ coors, int n,
                                                 const unsigned long long* __restrict__ tab,
                                                 int* __restrict__ deg,
                                                 int* __restrict__ adj) {
    int i = blockIdx.x * blockDim.x + threadIdx.x;
    if (i >= n) return;
    int4 cz = *(const int4*)(coors + 4 * i);
    int b = cz.x, z = cz.y, y = cz.z, x = cz.w;

    unsigned lins[13];
    unsigned hs[13];
    unsigned long long first[13];
    bool ok[13];

#pragma unroll
    for (int k = 0; k < 13; ++k) {                   // k compile-time after unroll
        int dz = k / 9 - 1, dy = (k / 3) % 3 - 1, dx = k % 3 - 1;
        int nz = z + dz, ny = y + dy, nx = x + dx;
        ok[k] = (nz >= 0 && nz < CD && ny >= 0 && ny < CH && nx >= 0 && nx < CW);
        unsigned lin = (((unsigned)b * CD + (unsigned)nz) * CH + (unsigned)ny) * CW + (unsigned)nx;
        lins[k] = lin;
        hs[k] = (lin * 2654435761u) >> (32u - HBITS); // always in-range: safe to load
        first[k] = tab[hs[k]];                        // 13 independent loads in flight
    }

#pragma unroll
    for (int k = 0; k < 13; ++k) {
        if (!ok[k]) continue;
        unsigned long long v = first[k];
        int j = -1;
        if ((unsigned)v == lins[k]) {
            j = (int)(v >> 32);
        } else if (v != EMPTY64) {                    // rare: continue probing from h+1
            unsigned h = (hs[k] + 1u) & HMASK;
            while (true) {
                v = tab[h];
                if ((unsigned)v == lins[k]) { j = (int)(v >> 32); break; }
                if (v == EMPTY64) break;
                h = (h + 1u) & HMASK;
            }
        }
        if (j >= 0) {
            int si = atomicAdd(&deg[i], 1);
            if (si < MAXD) adj[(size_t)i * MAXD + si] = (j << 5) | k;
            int sj = atomicAdd(&deg[j], 1);
            if (sj < MAXD) adj[(size_t)j * MAXD + sj] = (i << 5) | (26 - k);
        }
    }
}

// ---------------- dense tile: out[p] = x[p] @ P (R10/R11/R14-verified) -------------
// 128 points/block, 4 waves = 2 point-groups x 2 channel-halves. acc[32] static.
// X in LDS (coalesced float4 in, stride-65 pad). P rows via uniform s_load.
// Barrier between compute-read and in-place write-back (both halves read full rows).

#define GSTRIDE 65

__global__ __launch_bounds__(256, 4) void dense_tile(const float* __restrict__ xin,
                                                     float* __restrict__ xout,
                                                     const float* __restrict__ P,
                                                     int n) {
    __shared__ float Xs[128 * GSTRIDE];   // 33,280 B -> 4 blocks/CU
    int t = threadIdx.x;
    int lane = t & 63;
    int wv = t >> 6;
    int base = blockIdx.x * 128;

#pragma unroll
    for (int it = 0; it < 8; ++it) {                // global -> LDS, coalesced
        int f = it * 256 + t;                       // float4 id 0..2047
        int row = f >> 4, c4 = f & 15;
        int gr = base + row;
        int src = gr < n ? gr : n - 1;
        float4 v = *(const float4*)(xin + (size_t)src * 64 + c4 * 4);
        float* d = &Xs[row * GSTRIDE + c4 * 4];
        d[0] = v.x; d[1] = v.y; d[2] = v.z; d[3] = v.w;
    }
    __syncthreads();

    int g = wv >> 1;                                // point-group (0/1)
    int h = __builtin_amdgcn_readfirstlane((wv & 1) * 32);   // channel half, uniform
    int myrow = g * 64 + lane;
    const float* xr = &Xs[myrow * GSTRIDE];
    float acc[32];
#pragma unroll
    for (int o = 0; o < 32; ++o) acc[o] = 0.f;
#pragma unroll 4
    for (int c = 0; c < 64; ++c) {
        float xc = xr[c];
        const float* wr = P + c * 64 + h;           // uniform -> s_load
#pragma unroll
        for (int o = 0; o < 32; ++o) acc[o] = fmaf(xc, wr[o], acc[o]);
    }
    __syncthreads();                                // all reads of Xs done (R10 race fix)
    float* orow = &Xs[myrow * GSTRIDE + h];         // two waves: same row, disjoint halves
#pragma unroll
    for (int o = 0; o < 32; ++o) orow[o] = acc[o];
    __syncthreads();
#pragma unroll
    for (int it = 0; it < 8; ++it) {                // LDS -> global, coalesced
        int f = it * 256 + t;
        int row = f >> 4, c4 = f & 15;
        int gr = base + row;
        if (gr < n) {
            const float* s = &Xs[row * GSTRIDE + c4 * 4];
            float4 v = make_float4(s[0], s[1], s[2], s[3]);
            *(float4*)(xout + (size_t)gr * 64 + c4 * 4) = v;
        }
    }
}

// ---------------- fused S-layer (R8-verified): deg>0 points, center + taps --------

__global__ __launch_bounds__(256) void s_layer(const float* __restrict__ xin,
                                               float* __restrict__ xout,
                                               const float* __restrict__ Wl,   // [27][64][64]
                                               const int* __restrict__ deg,
                                               const int* __restrict__ adj,
                                               int n) {
    int wv  = (int)((blockIdx.x * blockDim.x + threadIdx.x) >> 6);
    int nwv = (int)((gridDim.x * blockDim.x) >> 6);
    int lane = threadIdx.x & 63;
    int nchunk = (n + 63) >> 6;
    const float* Wc = Wl + 13 * 4096;

    for (int ch = wv; ch < nchunk; ch += nwv) {
        int base = ch << 6;
        int p = base + lane;
        int dl = (p < n) ? deg[p] : 0;
        unsigned long long m = __ballot(dl != 0);
        while (m) {
            int bpos = (int)__ffsll(m) - 1;
            m &= m - 1;
            int i = base + bpos;
            int d = __shfl(dl, bpos);
            if (d > MAXD) d = MAXD;
            float xi = xin[(size_t)i * 64 + lane];
            float a0 = 0.f, a1 = 0.f;
#pragma unroll
            for (int c = 0; c < 64; c += 2) {
                a0 = fmaf(__shfl(xi, c),     Wc[c * 64 + lane],       a0);
                a1 = fmaf(__shfl(xi, c + 1), Wc[(c + 1) * 64 + lane], a1);
            }
            for (int e = 0; e < d; ++e) {
                int ent = adj[(size_t)i * MAXD + e];    // uniform -> broadcast
                int j = ent >> 5, k = ent & 31;
                float xj = xin[(size_t)j * 64 + lane];
                const float* Wk = Wl + k * 4096;
#pragma unroll
                for (int c = 0; c < 64; c += 2) {
                    a0 = fmaf(__shfl(xj, c),     Wk[c * 64 + lane],       a0);
                    a1 = fmaf(__shfl(xj, c + 1), Wk[(c + 1) * 64 + lane], a1);
                }
            }
            xout[(size_t)i * 64 + lane] = a0 + a1;
        }
    }
}

// ---------------- launch ----------------

extern "C" void kernel_launch(void* const* d_in, const int* in_sizes, int n_in,
                              void* d_out, int out_size, void* d_ws, size_t ws_size,
                              hipStream_t stream) {
    const float* features = (const float*)d_in[0];
    const float* Ws       = (const float*)d_in[1];   // [3][27][64][64]
    const int*   coors    = (const int*)d_in[2];
    int n = in_sizes[0] / 64;

    char* p = (char*)d_ws;
    unsigned long long* tab = (unsigned long long*)p; p += (size_t)HSIZE * 8;
    int* deg = (int*)p;                               p += (((size_t)n * 4 + 255) & ~255ull);
    int* adj = (int*)p;                               p += (((size_t)n * MAXD * 4 + 255) & ~255ull);
    float* bufA = (float*)p;                          p += (((size_t)n * 256 + 255) & ~255ull);
    float* bufB = (float*)p;                          p += (((size_t)n * 256 + 255) & ~255ull);
    float* T  = (float*)p;                            p += 16384;
    float* P  = (float*)p;                            p += 16384;
    float* out = (float*)d_out;

    const float* W0 = Ws + 0 * 27 * 4096;
    const float* W1 = Ws + 1 * 27 * 4096;
    const float* W2 = Ws + 2 * 27 * 4096;

    int nfill = (HSIZE + 255) / 256;                 // covers HSIZE and n
    setup<<<nfill + 16, 256, 0, stream>>>(tab, deg, n, Ws, T, nfill);
    int nins = (n + 255) / 256;
    hash_insert<<<nins + 16, 256, 0, stream>>>(coors, n, tab, T, Ws, P, nins);
    build_adj<<<(n + 255) / 256, 256, 0, stream>>>(coors, n, tab, deg, adj);

    // dense collapsed 3-layer pass: out = features @ P
    dense_tile<<<(n + 127) / 128, 256, 0, stream>>>(features, out, P, n);

    // S-pass (closed set, deg>0): fused center+taps per layer; overwrites out rows
    s_layer<<<512, 256, 0, stream>>>(features, bufA, W0, deg, adj, n);
    s_layer<<<512, 256, 0, stream>>>(bufA, bufB, W1, deg, adj, n);
    s_layer<<<512, 256, 0, stream>>>(bufB, out, W2, deg, adj, n);
}

// Round 18
// 145.529 us; speedup vs baseline: 1.0696x; 1.0696x over previous
//
#include <hip/hip_runtime.h>

#define HBITS 19u
#define HSIZE (1u << HBITS)
#define HMASK (HSIZE - 1u)
#define MAXD  27                  // geometric max neighbors (26) + slack
#define EMPTY64 0xFFFFFFFFFFFFFFFFull

constexpr int CD = 41, CH = 1024, CW = 1024;

// ---------------- setup: clear hash table + deg; 16 extra blocks: T = W0c@W1c ------

__global__ __launch_bounds__(256) void setup(unsigned long long* __restrict__ tab,
                                             int* __restrict__ deg, int n,
                                             const float* __restrict__ Ws,
                                             float* __restrict__ T,
                                             int nfill) {
    if ((int)blockIdx.x >= nfill) {
        // parallel weight product, mm64-style: 1 elem/thread, dual chains
        int e = ((int)blockIdx.x - nfill) * 256 + threadIdx.x;   // 0..4095
        int r = e >> 6, c = e & 63;
        const float* W0 = Ws + (0 * 27 + 13) * 4096;
        const float* W1 = Ws + (1 * 27 + 13) * 4096;
        float s0 = 0.f, s1 = 0.f;
#pragma unroll
        for (int k = 0; k < 64; k += 2) {
            s0 = fmaf(W0[r * 64 + k],     W1[k * 64 + c],       s0);
            s1 = fmaf(W0[r * 64 + k + 1], W1[(k + 1) * 64 + c], s1);
        }
        T[e] = s0 + s1;
        return;
    }
    unsigned i = blockIdx.x * 256u + threadIdx.x;
    if (i < HSIZE) tab[i] = EMPTY64;
    if (i < (unsigned)n) deg[i] = 0;
}

// ---------------- hash insert; 16 extra blocks: P = T@W2c ----------------

__global__ __launch_bounds__(256) void hash_insert(const int* __restrict__ coors, int n,
                                                   unsigned long long* __restrict__ tab,
                                                   const float* __restrict__ T,
                                                   const float* __restrict__ Ws,
                                                   float* __restrict__ P,
                                                   int nins) {
    if ((int)blockIdx.x >= nins) {
        int e = ((int)blockIdx.x - nins) * 256 + threadIdx.x;    // 0..4095
        int r = e >> 6, c = e & 63;
        const float* W2 = Ws + (2 * 27 + 13) * 4096;
        float s0 = 0.f, s1 = 0.f;
#pragma unroll
        for (int k = 0; k < 64; k += 2) {
            s0 = fmaf(T[r * 64 + k],     W2[k * 64 + c],       s0);
            s1 = fmaf(T[r * 64 + k + 1], W2[(k + 1) * 64 + c], s1);
        }
        P[e] = s0 + s1;
        return;
    }
    int i = blockIdx.x * 256 + threadIdx.x;
    if (i >= n) return;
    int b = coors[4 * i], z = coors[4 * i + 1], y = coors[4 * i + 2], x = coors[4 * i + 3];
    unsigned lin = (((unsigned)b * CD + (unsigned)z) * CH + (unsigned)y) * CW + (unsigned)x;
    unsigned h = (lin * 2654435761u) >> (32u - HBITS);
    unsigned long long rec = ((unsigned long long)(unsigned)i << 32) | (unsigned long long)lin;
    while (true) {
        unsigned long long prev = atomicCAS(&tab[h], EMPTY64, rec);
        if (prev == EMPTY64) break;
        h = (h + 1u) & HMASK;
    }
}

__device__ __forceinline__ int hash_lookup(unsigned lin, const unsigned long long* __restrict__ tab) {
    unsigned h = (lin * 2654435761u) >> (32u - HBITS);
    while (true) {
        unsigned long long v = tab[h];
        if ((unsigned)v == lin) return (int)(v >> 32);
        if (v == EMPTY64) return -1;
        h = (h + 1u) & HMASK;
    }
}

// ---------------- adjacency build: one thread per (point, tap<13) ----------------
// mirror symmetry: finding (i,k,j) also records (j,26-k,i). ONLY scattered atomics
// (R8-verified: no hot counter lines). Max-TLP decomposition (R17 showed the
// ILP-batched one-thread-per-point variant is 10us slower at 13x fewer waves).

__global__ __launch_bounds__(256) void build_adj(const int* __restrict__ coors, int n,
                                                 const unsigned long long* __restrict__ tab,
                                                 int* __restrict__ deg,
                                                 int* __restrict__ adj) {
    int tid = blockIdx.x * blockDim.x + threadIdx.x;
    if (tid >= n * 13) return;
    int i = tid / 13;
    int k = tid - i * 13;
    int b = coors[4 * i], z = coors[4 * i + 1], y = coors[4 * i + 2], x = coors[4 * i + 3];
    int dz = k / 9 - 1, dy = (k / 3) % 3 - 1, dx = k % 3 - 1;
    int nz = z + dz, ny = y + dy, nx = x + dx;
    if (nz < 0 || nz >= CD || ny < 0 || ny >= CH || nx < 0 || nx >= CW) return;
    unsigned lin = (((unsigned)b * CD + (unsigned)nz) * CH + (unsigned)ny) * CW + (unsigned)nx;
    int j = hash_lookup(lin, tab);
    if (j < 0) return;
    int si = atomicAdd(&deg[i], 1);
    if (si < MAXD) adj[(size_t)i * MAXD + si] = (j << 5) | k;
    int sj = atomicAdd(&deg[j], 1);
    if (sj < MAXD) adj[(size_t)j * MAXD + sj] = (i << 5) | (26 - k);
}

// ---------------- dense tile: out[p] = x[p] @ P (R10/R11/R14/R16-verified) ---------
// 128 points/block, 4 waves = 2 point-groups x 2 channel-halves. acc[32] static.
// X in LDS (coalesced float4 in, stride-65 pad). P rows via uniform s_load.
// Barrier between compute-read and in-place write-back (both halves read full rows).

#define GSTRIDE 65

__global__ __launch_bounds__(256, 4) void dense_tile(const float* __restrict__ xin,
                                                     float* __restrict__ xout,
                                                     const float* __restrict__ P,
                                                     int n) {
    __shared__ float Xs[128 * GSTRIDE];   // 33,280 B -> 4 blocks/CU
    int t = threadIdx.x;
    int lane = t & 63;
    int wv = t >> 6;
    int base = blockIdx.x * 128;

#pragma unroll
    for (int it = 0; it < 8; ++it) {                // global -> LDS, coalesced
        int f = it * 256 + t;                       // float4 id 0..2047
        int row = f >> 4, c4 = f & 15;
        int gr = base + row;
        int src = gr < n ? gr : n - 1;
        float4 v = *(const float4*)(xin + (size_t)src * 64 + c4 * 4);
        float* d = &Xs[row * GSTRIDE + c4 * 4];
        d[0] = v.x; d[1] = v.y; d[2] = v.z; d[3] = v.w;
    }
    __syncthreads();

    int g = wv >> 1;                                // point-group (0/1)
    int h = __builtin_amdgcn_readfirstlane((wv & 1) * 32);   // channel half, uniform
    int myrow = g * 64 + lane;
    const float* xr = &Xs[myrow * GSTRIDE];
    float acc[32];
#pragma unroll
    for (int o = 0; o < 32; ++o) acc[o] = 0.f;
#pragma unroll 4
    for (int c = 0; c < 64; ++c) {
        float xc = xr[c];
        const float* wr = P + c * 64 + h;           // uniform -> s_load
#pragma unroll
        for (int o = 0; o < 32; ++o) acc[o] = fmaf(xc, wr[o], acc[o]);
    }
    __syncthreads();                                // all reads of Xs done (R10 race fix)
    float* orow = &Xs[myrow * GSTRIDE + h];         // two waves: same row, disjoint halves
#pragma unroll
    for (int o = 0; o < 32; ++o) orow[o] = acc[o];
    __syncthreads();
#pragma unroll
    for (int it = 0; it < 8; ++it) {                // LDS -> global, coalesced
        int f = it * 256 + t;
        int row = f >> 4, c4 = f & 15;
        int gr = base + row;
        if (gr < n) {
            const float* s = &Xs[row * GSTRIDE + c4 * 4];
            float4 v = make_float4(s[0], s[1], s[2], s[3]);
            *(float4*)(xout + (size_t)gr * 64 + c4 * 4) = v;
        }
    }
}

// ---------------- fused S-layer (R8-verified): deg>0 points, center + taps --------

__global__ __launch_bounds__(256) void s_layer(const float* __restrict__ xin,
                                               float* __restrict__ xout,
                                               const float* __restrict__ Wl,   // [27][64][64]
                                               const int* __restrict__ deg,
                                               const int* __restrict__ adj,
                                               int n) {
    int wv  = (int)((blockIdx.x * blockDim.x + threadIdx.x) >> 6);
    int nwv = (int)((gridDim.x * blockDim.x) >> 6);
    int lane = threadIdx.x & 63;
    int nchunk = (n + 63) >> 6;
    const float* Wc = Wl + 13 * 4096;

    for (int ch = wv; ch < nchunk; ch += nwv) {
        int base = ch << 6;
        int p = base + lane;
        int dl = (p < n) ? deg[p] : 0;
        unsigned long long m = __ballot(dl != 0);
        while (m) {
            int bpos = (int)__ffsll(m) - 1;
            m &= m - 1;
            int i = base + bpos;
            int d = __shfl(dl, bpos);
            if (d > MAXD) d = MAXD;
            float xi = xin[(size_t)i * 64 + lane];
            float a0 = 0.f, a1 = 0.f;
#pragma unroll
            for (int c = 0; c < 64; c += 2) {
                a0 = fmaf(__shfl(xi, c),     Wc[c * 64 + lane],       a0);
                a1 = fmaf(__shfl(xi, c + 1), Wc[(c + 1) * 64 + lane], a1);
            }
            for (int e = 0; e < d; ++e) {
                int ent = adj[(size_t)i * MAXD + e];    // uniform -> broadcast
                int j = ent >> 5, k = ent & 31;
                float xj = xin[(size_t)j * 64 + lane];
                const float* Wk = Wl + k * 4096;
#pragma unroll
                for (int c = 0; c < 64; c += 2) {
                    a0 = fmaf(__shfl(xj, c),     Wk[c * 64 + lane],       a0);
                    a1 = fmaf(__shfl(xj, c + 1), Wk[(c + 1) * 64 + lane], a1);
                }
            }
            xout[(size_t)i * 64 + lane] = a0 + a1;
        }
    }
}

// ---------------- launch ----------------

extern "C" void kernel_launch(void* const* d_in, const int* in_sizes, int n_in,
                              void* d_out, int out_size, void* d_ws, size_t ws_size,
                              hipStream_t stream) {
    const float* features = (const float*)d_in[0];
    const float* Ws       = (const float*)d_in[1];   // [3][27][64][64]
    const int*   coors    = (const int*)d_in[2];
    int n = in_sizes[0] / 64;

    char* p = (char*)d_ws;
    unsigned long long* tab = (unsigned long long*)p; p += (size_t)HSIZE * 8;
    int* deg = (int*)p;                               p += (((size_t)n * 4 + 255) & ~255ull);
    int* adj = (int*)p;                               p += (((size_t)n * MAXD * 4 + 255) & ~255ull);
    float* bufA = (float*)p;                          p += (((size_t)n * 256 + 255) & ~255ull);
    float* bufB = (float*)p;                          p += (((size_t)n * 256 + 255) & ~255ull);
    float* T  = (float*)p;                            p += 16384;
    float* P  = (float*)p;                            p += 16384;
    float* out = (float*)d_out;

    const float* W0 = Ws + 0 * 27 * 4096;
    const float* W1 = Ws + 1 * 27 * 4096;
    const float* W2 = Ws + 2 * 27 * 4096;

    int nfill = (HSIZE + 255) / 256;                 // covers HSIZE and n
    setup<<<nfill + 16, 256, 0, stream>>>(tab, deg, n, Ws, T, nfill);
    int nins = (n + 255) / 256;
    hash_insert<<<nins + 16, 256, 0, stream>>>(coors, n, tab, T, Ws, P, nins);
    build_adj<<<(n * 13 + 255) / 256, 256, 0, stream>>>(coors, n, tab, deg, adj);

    // dense collapsed 3-layer pass: out = features @ P
    dense_tile<<<(n + 127) / 128, 256, 0, stream>>>(features, out, P, n);

    // S-pass (closed set, deg>0): fused center+taps per layer; overwrites out rows
    s_layer<<<512, 256, 0, stream>>>(features, bufA, W0, deg, adj, n);
    s_layer<<<512, 256, 0, stream>>>(bufA, bufB, W1, deg, adj, n);
    s_layer<<<512, 256, 0, stream>>>(bufB, out, W2, deg, adj, n);
}